// Round 4
// baseline (3806.640 us; speedup 1.0000x reference)
//
#include <hip/hip_runtime.h>
#include <math.h>

#define TT 512
#define DD 1024
#define BB 32
#define G3D (3*DD)
#define NBLK 64          // k_gru blocks; each owns 16 h-columns

typedef _Float16 f16;
typedef _Float16 f16x2 __attribute__((ext_vector_type(2)));
typedef _Float16 f16x4 __attribute__((ext_vector_type(4)));
typedef _Float16 f16x8 __attribute__((ext_vector_type(8)));
typedef float f32x4 __attribute__((ext_vector_type(4)));
typedef unsigned u32x2 __attribute__((ext_vector_type(2)));
typedef unsigned u32x4 __attribute__((ext_vector_type(4)));
typedef unsigned long long u64;

// h exchange: 2 parity slots of TAGGED dwords, one dword per f16 column value:
//   word = (tag << 16) | f16_bits,  tag = step that CONSUMES this value.
// Blocked layout (dword index): ((col>>5)*32 + row)*32 + (col&31)
//   -> consumer fragment loads are dense 2KB regions, fully line-coalesced.
// A 4B-aligned dword cannot tear, so each word self-validates; the u64
// publish may split into dwords but each half carries its own tag.
// Slot = 32*32*32 dwords = 131072 B.
// IMPORTANT (round-3 lesson): publish must be AGENT-scope (sc0, LLC-backed).
// sc1 stores go system-scope -> h bounced through HBM, +118MB FETCH, 1.6x slower.
#define HSLOT_BYTES 131072

// ---------------------------------------------------------------- kernel A
// Convert weights fp32->fp16, init tagged h exchange buffer.
// Slot0 (consumed at t=0): tag 0, payload f16(0) -> whole word 0.
// Slot1 (consumed first at t=1): sentinel tag 0xFFFF never matches (t<=512).
__global__ void k_convert(const float* __restrict__ Wih, const float* __restrict__ Whh,
                          f16* __restrict__ Wih16, f16* __restrict__ Whh16,
                          unsigned* __restrict__ hX) {
    int idx = blockIdx.x * 256 + threadIdx.x;
    int n = G3D * DD;
    if (idx < n) {
        Wih16[idx] = (f16)Wih[idx];
        Whh16[idx] = (f16)Whh[idx];
    }
    if (idx < 32768)        hX[idx] = 0u;
    else if (idx < 65536)   hX[idx] = 0xFFFF0000u;
}

// ---------------------------------------------------------------- kernel B
// GI[16384][3072] = h_enc[16384][1024] * Wih^T + b_ih  (fp16 out)
#define BM 128
#define BN 128
#define BK 32
#define LDA 40

__global__ __launch_bounds__(256) void k_pregemm(
    const float* __restrict__ X,
    const f16*   __restrict__ W16,
    const float* __restrict__ bih,
    f16* __restrict__ GI)
{
    __shared__ f16 As[BM * LDA];
    __shared__ f16 Bs[BN * LDA];
    const int tid  = threadIdx.x;
    const int lane = tid & 63;
    const int wave = tid >> 6;
    const int wr = wave >> 1, wc = wave & 1;
    const int m0 = blockIdx.y * BM;
    const int n0 = blockIdx.x * BN;
    const int mfrag = lane & 15;
    const int qfrag = lane >> 4;

    f32x4 acc[4][4] = {};

    for (int kt = 0; kt < DD; kt += BK) {
        __syncthreads();
        {
            int row = tid >> 3;
            int c   = tid & 7;
            #pragma unroll
            for (int p = 0; p < 4; ++p) {
                int r = row + p * 32;
                float4 v = *(const float4*)(X + (size_t)(m0 + r) * DD + kt + c * 4);
                f16x4 hv = { (f16)v.x, (f16)v.y, (f16)v.z, (f16)v.w };
                *(f16x4*)(As + r * LDA + c * 4) = hv;
            }
        }
        {
            int row = tid >> 2;
            int c   = tid & 3;
            #pragma unroll
            for (int p = 0; p < 2; ++p) {
                int r = row + p * 64;
                f16x8 v = *(const f16x8*)(W16 + (size_t)(n0 + r) * DD + kt + c * 8);
                *(f16x8*)(Bs + r * LDA + c * 8) = v;
            }
        }
        __syncthreads();
        f16x8 af[4], bf[4];
        #pragma unroll
        for (int i = 0; i < 4; ++i)
            af[i] = *(const f16x8*)(As + (wr * 64 + i * 16 + mfrag) * LDA + qfrag * 8);
        #pragma unroll
        for (int j = 0; j < 4; ++j)
            bf[j] = *(const f16x8*)(Bs + (wc * 64 + j * 16 + mfrag) * LDA + qfrag * 8);
        #pragma unroll
        for (int i = 0; i < 4; ++i)
            #pragma unroll
            for (int j = 0; j < 4; ++j)
                acc[i][j] = __builtin_amdgcn_mfma_f32_16x16x32_f16(af[i], bf[j], acc[i][j], 0, 0, 0);
    }
    #pragma unroll
    for (int j = 0; j < 4; ++j) {
        int col = n0 + wc * 64 + j * 16 + mfrag;
        float bias = bih[col];
        #pragma unroll
        for (int i = 0; i < 4; ++i) {
            int rowb = m0 + wr * 64 + i * 16 + qfrag * 4;
            #pragma unroll
            for (int r = 0; r < 4; ++r)
                GI[(size_t)(rowb + r) * G3D + col] = (f16)(acc[i][j][r] + bias);
        }
    }
}

// ---------------------------------------------------------------- kernel C
// Persistent recurrent kernel: 64 blocks x 256 threads (4 waves = K-quarters).
// Tagged-word sync, no flags, no publish drain:
//   - publish: one u64 __hip_atomic_store AGENT (LLC-resident, fire&forget)
//   - consume: STRONG sentinel spin (lane l watches producer block 16kq+(l>>2),
//     producer wave l&3 -- the last word that wave stores), then ONE bulk
//     dwordx4 load pass with per-dword tag validation (retry rare).
// Safety (proven r3): block P publishes tag t+1 only after validating ALL its
// tag-t reads; transitively nobody overwrites slot words still being read.
// Max skew 1 step; tags monotone <=512, no ABA.
#define WROW 1032    // LDS row stride in halves (1024 + 8 pad; 2064 B, 16B-mult)

__global__ __launch_bounds__(256, 1) void k_gru(
    const f16* __restrict__ Whh16,   // [3072][1024]
    const f16* __restrict__ GI,      // [16384][3072]
    const float* __restrict__ bhh,   // [3072]
    float* __restrict__ out,         // [32][512][1024] fp32
    unsigned* __restrict__ hX)       // [2] tagged h slots
{
    __shared__ f16 Ws[48 * WROW];           // 99072 B
    __shared__ float red[4][3][32][20];     // 30720 B, col-pad 16->20
    __shared__ float h32[32][18];
    __shared__ float bh_s[3][16];

    const int tid  = threadIdx.x;
    const int lane = tid & 63;
    const int kq   = tid >> 6;        // wave id = K quarter (256)
    const int bid  = blockIdx.x;
    const int j0   = bid * 16;
    const int mfrag = lane & 15;
    const int qk    = lane >> 4;      // 0..3

    // stage W_hh slice into LDS: LDS row r -> gate r>>4, col n=r&15
    for (int i = tid; i < 48 * 128; i += 256) {
        int r = i >> 7, c = i & 127;
        int grow = (r >> 4) * DD + j0 + (r & 15);
        *(f16x8*)(Ws + r * WROW + c * 8) =
            *(const f16x8*)(Whh16 + (size_t)grow * DD + c * 8);
    }
    for (int i = tid; i < 32 * 18; i += 256) ((float*)h32)[i] = 0.f;
    if (tid < 48) bh_s[tid >> 4][tid & 15] = bhh[(tid >> 4) * DD + j0 + (tid & 15)];
    __syncthreads();

    const int bg = tid >> 3;          // combine: batch row 0..31
    const int c2 = (tid & 7) * 2;     // combine: col pair 0..14

    // strong sentinel: lane l watches producer block P=16kq+(l>>2), wave w=l&3.
    // That wave's last thread (tid=64w+63) stores bg=8w+7, cols {14,15} of P:
    // dword idx = (P>>1)*1024 + (8w+7)*32 + 16*(P&1) + 15.
    const int sP = 16 * kq + (lane >> 2);
    const int sw = lane & 3;
    const unsigned sidx = (unsigned)(sP >> 1) * 1024u + (unsigned)(8 * sw + 7) * 32u
                        + (unsigned)(sP & 1) * 16u + 15u;

    f16x2 giv[3], givn[3];
    #pragma unroll
    for (int g = 0; g < 3; ++g)
        giv[g] = *(const f16x2*)(GI + (size_t)bg * TT * G3D + g * DD + j0 + c2);

    for (int t = 0; t < TT; ++t) {
        const int par = t & 1;
        const unsigned exph = ((unsigned)t) << 16;
        const u64 slotR = (u64)hX + (u64)par * HSLOT_BYTES;
        const u64 slotW = (u64)hX + (u64)(par ^ 1) * HSLOT_BYTES;

        // ---- strong sentinel spin: one dword per producer-wave, 64 lanes
        {
            u64 saddr = slotR + 4ull * sidx;
            for (;;) {
                unsigned s;
                asm volatile("global_load_dword %0, %1, off sc0 sc1"
                             : "=v"(s) : "v"(saddr) : "memory");
                asm volatile("s_waitcnt vmcnt(0)" ::: "memory");
                __builtin_amdgcn_sched_barrier(0);
                if (!__any((int)((s ^ exph) & 0xFFFF0000u))) break;
                __builtin_amdgcn_s_sleep(1);
            }
        }

        // ---- bulk tagged load + per-dword validation (retry rare now)
        f16x8 af[8][2];
        for (;;) {
            u32x4 st[8][2][2];
            #pragma unroll
            for (int it = 0; it < 8; ++it)
                #pragma unroll
                for (int rt = 0; rt < 2; ++rt) {
                    u64 base = slotR + 4ull * (u64)((((kq * 8 + it) * 32 + rt * 16 + mfrag) * 32) + qk * 8);
                    asm volatile("global_load_dwordx4 %0, %1, off sc0 sc1"
                                 : "=v"(st[it][rt][0]) : "v"(base) : "memory");
                    asm volatile("global_load_dwordx4 %0, %1, off sc0 sc1"
                                 : "=v"(st[it][rt][1]) : "v"(base + 16) : "memory");
                }
            asm volatile("s_waitcnt vmcnt(0)" ::: "memory");
            __builtin_amdgcn_sched_barrier(0);
            unsigned bad = 0;
            #pragma unroll
            for (int it = 0; it < 8; ++it)
                #pragma unroll
                for (int rt = 0; rt < 2; ++rt) {
                    u32x4 a = st[it][rt][0];
                    u32x4 b = st[it][rt][1];
                    bad |= (a.x ^ exph) | (a.y ^ exph) | (a.z ^ exph) | (a.w ^ exph)
                         | (b.x ^ exph) | (b.y ^ exph) | (b.z ^ exph) | (b.w ^ exph);
                    union { unsigned u[4]; f16x8 v; } fr;
                    fr.u[0] = (a.x & 0xFFFFu) | (a.y << 16);
                    fr.u[1] = (a.z & 0xFFFFu) | (a.w << 16);
                    fr.u[2] = (b.x & 0xFFFFu) | (b.y << 16);
                    fr.u[3] = (b.z & 0xFFFFu) | (b.w << 16);
                    af[it][rt] = fr.v;
                }
            if (!__any((int)(bad & 0xFFFF0000u))) break;
            __builtin_amdgcn_s_sleep(1);
        }

        // gi prefetch for t+1: issued AFTER the spin so its HBM latency never
        // sits on the spin's vmcnt(0); hides under MFMA + reduction instead.
        {
            int tn = (t + 1 < TT) ? t + 1 : t;
            #pragma unroll
            for (int g = 0; g < 3; ++g)
                givn[g] = *(const f16x2*)(GI + ((size_t)bg * TT + tn) * G3D + g * DD + j0 + c2);
        }

        // MFMA: B-frags streamed from LDS (ds_read_b128), weights stay on-CU
        f32x4 acc[3][2] = {};
        #pragma unroll
        for (int it = 0; it < 8; ++it) {
            f16x8 bf[3];
            #pragma unroll
            for (int g = 0; g < 3; ++g)
                bf[g] = *(const f16x8*)(Ws + (g * 16 + mfrag) * WROW + kq * 256 + it * 32 + qk * 8);
            #pragma unroll
            for (int g = 0; g < 3; ++g)
                #pragma unroll
                for (int rt = 0; rt < 2; ++rt)
                    acc[g][rt] = __builtin_amdgcn_mfma_f32_16x16x32_f16(
                        af[it][rt], bf[g], acc[g][rt], 0, 0, 0);
        }

        // dump K-partials. C/D: col=lane&15, row=(lane>>4)*4+reg
        #pragma unroll
        for (int g = 0; g < 3; ++g)
            #pragma unroll
            for (int rt = 0; rt < 2; ++rt)
                #pragma unroll
                for (int r = 0; r < 4; ++r)
                    red[kq][g][rt * 16 + qk * 4 + r][mfrag] = acc[g][rt][r];
        // LDS-visibility barrier only (no vmcnt drain -> stores stay in flight)
        asm volatile("s_waitcnt lgkmcnt(0)\n\ts_barrier" ::: "memory");

        // combine: thread -> batch bg, cols {c2, c2+1}
        float hnew[2];
        {
            float2 gr = make_float2(0.f, 0.f), gz = gr, gn = gr;
            #pragma unroll
            for (int q = 0; q < 4; ++q) {
                float2 vr = *(const float2*)&red[q][0][bg][c2];
                float2 vz = *(const float2*)&red[q][1][bg][c2];
                float2 vn = *(const float2*)&red[q][2][bg][c2];
                gr.x += vr.x; gr.y += vr.y;
                gz.x += vz.x; gz.y += vz.y;
                gn.x += vn.x; gn.y += vn.y;
            }
            #pragma unroll
            for (int cc = 0; cc < 2; ++cc) {
                float ghr = cc ? gr.y : gr.x;
                float ghz = cc ? gz.y : gz.x;
                float ghn = cc ? gn.y : gn.x;
                float pr = (float)giv[0][cc] + ghr + bh_s[0][c2 + cc];
                float pz = (float)giv[1][cc] + ghz + bh_s[1][c2 + cc];
                float r  = 1.f / (1.f + __expf(-pr));
                float z  = 1.f / (1.f + __expf(-pz));
                float pn = (float)giv[2][cc] + r * (ghn + bh_s[2][c2 + cc]);
                float e  = __expf(-2.f * fabsf(pn));
                float tn = (1.f - e) / (1.f + e);
                tn = pn < 0.f ? -tn : tn;
                float hold = h32[bg][c2 + cc];
                float hn2 = tn + z * (hold - tn);
                h32[bg][c2 + cc] = hn2;
                hnew[cc] = hn2;
            }
            // tagged publish: ONE u64 agent-scope atomic (sc0, LLC-resident).
            // Each dword half self-validates, so dword-level tearing is fine.
            union { unsigned short s; f16 h; } q0, q1;
            q0.h = (f16)hnew[0]; q1.h = (f16)hnew[1];
            unsigned tagw = ((unsigned)(t + 1)) << 16;
            u64 w = ((u64)(tagw | (unsigned)q1.s) << 32) | (u64)(tagw | (unsigned)q0.s);
            int col = j0 + c2;
            unsigned widx = (unsigned)(col >> 5) * 1024u + (unsigned)bg * 32u + (unsigned)(col & 31);
            __hip_atomic_store((u64*)(slotW + 4ull * widx), w,
                               __ATOMIC_RELAXED, __HIP_MEMORY_SCOPE_AGENT);
            // out store: plain, off the critical path, drained lazily
            *(float2*)(out + ((size_t)bg * TT + t) * DD + j0 + c2) = make_float2(hnew[0], hnew[1]);
        }

        // WAR protection for red (raw barrier; no vmcnt drain wanted)
        asm volatile("s_barrier" ::: "memory");

        giv[0] = givn[0]; giv[1] = givn[1]; giv[2] = givn[2];
    }
}

// ---------------------------------------------------------------- launch
extern "C" void kernel_launch(void* const* d_in, const int* in_sizes, int n_in,
                              void* d_out, int out_size, void* d_ws, size_t ws_size,
                              hipStream_t stream) {
    const float* h_enc = (const float*)d_in[0];
    const float* Wih   = (const float*)d_in[1];
    const float* Whh   = (const float*)d_in[2];
    const float* bih   = (const float*)d_in[3];
    const float* bhh   = (const float*)d_in[4];
    float* out = (float*)d_out;

    char* ws = (char*)d_ws;
    // ws layout: GI 100663296 | Wih16 6291456 | Whh16 6291456 | hX 262144
    f16* GI     = (f16*)(ws);
    f16* Wih16  = (f16*)(ws + 100663296);
    f16* Whh16  = (f16*)(ws + 106954752);
    unsigned* hX = (unsigned*)(ws + 113246208);

    hipLaunchKernelGGL(k_convert, dim3(12288), dim3(256), 0, stream,
                       Wih, Whh, Wih16, Whh16, hX);
    hipLaunchKernelGGL(k_pregemm, dim3(24, 128), dim3(256), 0, stream,
                       h_enc, Wih16, bih, GI);
    hipLaunchKernelGGL(k_gru, dim3(NBLK), dim3(256), 0, stream,
                       Whh16, GI, bhh, out, hX);
}

// Round 5
// 2155.247 us; speedup vs baseline: 1.7662x; 1.7662x over previous
//
#include <hip/hip_runtime.h>
#include <math.h>

#define TT 512
#define DD 1024
#define BB 32
#define G3D (3*DD)
#define NBLK 64          // k_gru blocks; each owns 16 h-columns

typedef _Float16 f16;
typedef _Float16 f16x2 __attribute__((ext_vector_type(2)));
typedef _Float16 f16x4 __attribute__((ext_vector_type(4)));
typedef _Float16 f16x8 __attribute__((ext_vector_type(8)));
typedef float f32x4 __attribute__((ext_vector_type(4)));
typedef unsigned long long u64;

// h exchange buffer: 2 parity slots, BLOCKED layout so consumer fragment
// loads are fully line-coalesced:
//   half index = ((col>>5)*32 + row)*32 + (col&31)
// Slot = 32*32*32 halves = 65536 B.
// Protocol (PROVEN r2, 1945us): publish 4B agent atomics -> vmcnt(0) drain ->
// syncthreads -> per-block epoch flag + 64-way fan-in poll -> syncthreads.
// Tagged/flag-free variants (r3: sc1 store bounced via HBM; r4: strong
// sentinel + bulk revalidation) were BOTH slower: 2x volume + full-bulk
// retries eat the saved trip. Do not revisit.
#define HSLOT_BYTES 65536

// ---------------------------------------------------------------- kernel A
__global__ void k_convert(const float* __restrict__ Wih, const float* __restrict__ Whh,
                          f16* __restrict__ Wih16, f16* __restrict__ Whh16,
                          u64* __restrict__ hX, unsigned int* __restrict__ flags) {
    int idx = blockIdx.x * 256 + threadIdx.x;
    int n = G3D * DD;
    if (idx < n) {
        Wih16[idx] = (f16)Wih[idx];
        Whh16[idx] = (f16)Whh[idx];
    }
    if (idx < 2 * HSLOT_BYTES / 8) hX[idx] = 0ull;   // h0 = 0, both slots
    if (idx < NBLK * 32) flags[idx] = 0u;            // 64 flags, 32-dword spacing
}

// ---------------------------------------------------------------- kernel B
// GI[16384][3072] = h_enc[16384][1024] * Wih^T + b_ih  (fp16 out)
#define BM 128
#define BN 128
#define BK 32
#define LDA 40

__global__ __launch_bounds__(256) void k_pregemm(
    const float* __restrict__ X,
    const f16*   __restrict__ W16,
    const float* __restrict__ bih,
    f16* __restrict__ GI)
{
    __shared__ f16 As[BM * LDA];
    __shared__ f16 Bs[BN * LDA];
    const int tid  = threadIdx.x;
    const int lane = tid & 63;
    const int wave = tid >> 6;
    const int wr = wave >> 1, wc = wave & 1;
    const int m0 = blockIdx.y * BM;
    const int n0 = blockIdx.x * BN;
    const int mfrag = lane & 15;
    const int qfrag = lane >> 4;

    f32x4 acc[4][4] = {};

    for (int kt = 0; kt < DD; kt += BK) {
        __syncthreads();
        {
            int row = tid >> 3;
            int c   = tid & 7;
            #pragma unroll
            for (int p = 0; p < 4; ++p) {
                int r = row + p * 32;
                float4 v = *(const float4*)(X + (size_t)(m0 + r) * DD + kt + c * 4);
                f16x4 hv = { (f16)v.x, (f16)v.y, (f16)v.z, (f16)v.w };
                *(f16x4*)(As + r * LDA + c * 4) = hv;
            }
        }
        {
            int row = tid >> 2;
            int c   = tid & 3;
            #pragma unroll
            for (int p = 0; p < 2; ++p) {
                int r = row + p * 64;
                f16x8 v = *(const f16x8*)(W16 + (size_t)(n0 + r) * DD + kt + c * 8);
                *(f16x8*)(Bs + r * LDA + c * 8) = v;
            }
        }
        __syncthreads();
        f16x8 af[4], bf[4];
        #pragma unroll
        for (int i = 0; i < 4; ++i)
            af[i] = *(const f16x8*)(As + (wr * 64 + i * 16 + mfrag) * LDA + qfrag * 8);
        #pragma unroll
        for (int j = 0; j < 4; ++j)
            bf[j] = *(const f16x8*)(Bs + (wc * 64 + j * 16 + mfrag) * LDA + qfrag * 8);
        #pragma unroll
        for (int i = 0; i < 4; ++i)
            #pragma unroll
            for (int j = 0; j < 4; ++j)
                acc[i][j] = __builtin_amdgcn_mfma_f32_16x16x32_f16(af[i], bf[j], acc[i][j], 0, 0, 0);
    }
    #pragma unroll
    for (int j = 0; j < 4; ++j) {
        int col = n0 + wc * 64 + j * 16 + mfrag;
        float bias = bih[col];
        #pragma unroll
        for (int i = 0; i < 4; ++i) {
            int rowb = m0 + wr * 64 + i * 16 + qfrag * 4;
            #pragma unroll
            for (int r = 0; r < 4; ++r)
                GI[(size_t)(rowb + r) * G3D + col] = (f16)(acc[i][j][r] + bias);
        }
    }
}

// ---------------------------------------------------------------- kernel C
// Persistent recurrent kernel: 64 blocks x 256 threads (4 waves = K-quarters).
// NEW vs r2 (protocol unchanged):
//   - W_hh B-fragments live in 96 VGPRs per lane (loop-invariant!) instead of
//     99KB LDS: kills 24 ds_read_b128/step + their 8-way bank conflicts
//     ((mfrag+qk)%8 quad aliasing) and all lgkm waits in the MFMA phase.
//   - out store issued BEFORE the publish drain: overlaps the HBM write with
//     the h-store ack instead of stalling the next step's af vmcnt(0).
//   - red col-pad 20->21: partial-dump ds_write_b32 4-way -> free 2-way.
__global__ __launch_bounds__(256, 1) void k_gru(
    const f16* __restrict__ Whh16,   // [3072][1024]
    const f16* __restrict__ GI,      // [16384][3072]
    const float* __restrict__ bhh,   // [3072]
    float* __restrict__ out,         // [32][512][1024] fp32
    f16* __restrict__ hX,            // [2] blocked h slots
    unsigned int* __restrict__ flags)// [64] epoch flags, 32-dword spacing
{
    __shared__ float red[4][3][32][21];     // 32256 B
    __shared__ float h32[32][18];
    __shared__ float bh_s[3][16];

    const int tid  = threadIdx.x;
    const int lane = tid & 63;
    const int kq   = tid >> 6;        // wave id = K quarter (256)
    const int bid  = blockIdx.x;
    const int j0   = bid * 16;
    const int mfrag = lane & 15;
    const int qk    = lane >> 4;      // 0..3

    // B-fragments -> registers, once. Lane (mfrag,qk) of wave kq holds
    // W_hh[g*DD + j0 + mfrag][kq*256 + it*32 + qk*8 ..+8] for it=0..7, g=0..2.
    f16x8 wb[8][3];
    #pragma unroll
    for (int it = 0; it < 8; ++it)
        #pragma unroll
        for (int g = 0; g < 3; ++g)
            wb[it][g] = *(const f16x8*)(Whh16 + (size_t)(g * DD + j0 + mfrag) * DD
                                        + kq * 256 + it * 32 + qk * 8);

    for (int i = tid; i < 32 * 18; i += 256) ((float*)h32)[i] = 0.f;
    if (tid < 48) bh_s[tid >> 4][tid & 15] = bhh[(tid >> 4) * DD + j0 + (tid & 15)];
    __syncthreads();

    const int bg = tid >> 3;          // combine: batch row 0..31
    const int c2 = (tid & 7) * 2;     // combine: col pair 0..14

    // prefetch gi for t=0
    f16x2 giv[3], givn[3];
    #pragma unroll
    for (int g = 0; g < 3; ++g)
        giv[g] = *(const f16x2*)(GI + (size_t)bg * TT * G3D + g * DD + j0 + c2);

    for (int t = 0; t < TT; ++t) {
        const int par = t & 1;

        // prefetch gi for t+1 (latency hides under af loads / MFMA)
        {
            int tn = (t + 1 < TT) ? t + 1 : t;
            #pragma unroll
            for (int g = 0; g < 3; ++g)
                givn[g] = *(const f16x2*)(GI + ((size_t)bg * TT + tn) * G3D + g * DD + j0 + c2);
        }

        // A-fragments of h from the blocked slot: per (it,rt) one coherent
        // dwordx4; wave's 64 lanes cover a dense 1KB region -> full 64B lines.
        f16x8 af[8][2];
        {
            const u64 hbase = (u64)hX + (u64)par * HSLOT_BYTES;
            #pragma unroll
            for (int it = 0; it < 8; ++it)
                #pragma unroll
                for (int rt = 0; rt < 2; ++rt) {
                    u64 addr = hbase + (u64)((((kq * 8 + it) * 32 + rt * 16 + mfrag) << 6) + (qk << 4));
                    asm volatile("global_load_dwordx4 %0, %1, off sc0 sc1"
                                 : "=v"(af[it][rt]) : "v"(addr) : "memory");
                }
        }
        asm volatile("s_waitcnt vmcnt(0)" ::: "memory");
        __builtin_amdgcn_sched_barrier(0);

        // MFMA: B-frags straight from registers; no LDS in this phase.
        f32x4 acc[3][2] = {};
        #pragma unroll
        for (int it = 0; it < 8; ++it)
            #pragma unroll
            for (int g = 0; g < 3; ++g)
                #pragma unroll
                for (int rt = 0; rt < 2; ++rt)
                    acc[g][rt] = __builtin_amdgcn_mfma_f32_16x16x32_f16(
                        af[it][rt], wb[it][g], acc[g][rt], 0, 0, 0);

        // dump K-partials. C/D: col=lane&15, row=(lane>>4)*4+reg
        #pragma unroll
        for (int g = 0; g < 3; ++g)
            #pragma unroll
            for (int rt = 0; rt < 2; ++rt)
                #pragma unroll
                for (int r = 0; r < 4; ++r)
                    red[kq][g][rt * 16 + qk * 4 + r][mfrag] = acc[g][rt][r];
        __syncthreads();

        // combine: thread -> batch bg, cols {c2, c2+1}
        float hnew[2];
        {
            float2 gr = make_float2(0.f, 0.f), gz = gr, gn = gr;
            #pragma unroll
            for (int q = 0; q < 4; ++q) {
                float2 vr = *(const float2*)&red[q][0][bg][c2];
                float2 vz = *(const float2*)&red[q][1][bg][c2];
                float2 vn = *(const float2*)&red[q][2][bg][c2];
                gr.x += vr.x; gr.y += vr.y;
                gz.x += vz.x; gz.y += vz.y;
                gn.x += vn.x; gn.y += vn.y;
            }
            #pragma unroll
            for (int cc = 0; cc < 2; ++cc) {
                float ghr = cc ? gr.y : gr.x;
                float ghz = cc ? gz.y : gz.x;
                float ghn = cc ? gn.y : gn.x;
                float pr = (float)giv[0][cc] + ghr + bh_s[0][c2 + cc];
                float pz = (float)giv[1][cc] + ghz + bh_s[1][c2 + cc];
                float r  = 1.f / (1.f + __expf(-pr));
                float z  = 1.f / (1.f + __expf(-pz));
                float pn = (float)giv[2][cc] + r * (ghn + bh_s[2][c2 + cc]);
                float e  = __expf(-2.f * fabsf(pn));
                float tn = (1.f - e) / (1.f + e);
                tn = pn < 0.f ? -tn : tn;
                float hold = h32[bg][c2 + cc];
                float hn2 = tn + z * (hold - tn);
                h32[bg][c2 + cc] = hn2;
                hnew[cc] = hn2;
            }
            // publish h(t+1): one 4B agent atomic into the blocked slot.
            union { unsigned u; f16x2 h; } pk;
            pk.h[0] = (f16)hnew[0]; pk.h[1] = (f16)hnew[1];
            int col = j0 + c2;
            unsigned hidx = ((unsigned)(col >> 5) * 32 + (unsigned)bg) * 16 + (unsigned)((col & 31) >> 1);
            unsigned int* hp = (unsigned int*)hX + (size_t)(par ^ 1) * (HSLOT_BYTES / 4);
            __hip_atomic_store(hp + hidx, pk.u, __ATOMIC_RELAXED, __HIP_MEMORY_SCOPE_AGENT);
            // out store issued NOW so its HBM ack overlaps the h-store ack in
            // the same drain (instead of stalling next step's af vmcnt(0)).
            *(float2*)(out + ((size_t)bg * TT + t) * DD + j0 + c2) = make_float2(hnew[0], hnew[1]);
        }

        // release: drain stores, then parallel per-block flag fan-in/out
        __builtin_amdgcn_s_waitcnt(0x0F70);   // vmcnt(0)
        __syncthreads();                      // all waves drained
        if (tid < NBLK) {
            if (tid == 0)
                __hip_atomic_store(flags + bid * 32, (unsigned)(t + 1),
                                   __ATOMIC_RELAXED, __HIP_MEMORY_SCOPE_AGENT);
            while (__hip_atomic_load(flags + tid * 32, __ATOMIC_RELAXED,
                                     __HIP_MEMORY_SCOPE_AGENT) < (unsigned)(t + 1))
                __builtin_amdgcn_s_sleep(1);
        }
        __syncthreads();

        giv[0] = givn[0]; giv[1] = givn[1]; giv[2] = givn[2];
    }
}

// ---------------------------------------------------------------- launch
extern "C" void kernel_launch(void* const* d_in, const int* in_sizes, int n_in,
                              void* d_out, int out_size, void* d_ws, size_t ws_size,
                              hipStream_t stream) {
    const float* h_enc = (const float*)d_in[0];
    const float* Wih   = (const float*)d_in[1];
    const float* Whh   = (const float*)d_in[2];
    const float* bih   = (const float*)d_in[3];
    const float* bhh   = (const float*)d_in[4];
    float* out = (float*)d_out;

    char* ws = (char*)d_ws;
    // ws layout: GI 100663296 | Wih16 6291456 | Whh16 6291456 | hX 131072 | flags 8192
    f16* GI     = (f16*)(ws);
    f16* Wih16  = (f16*)(ws + 100663296);
    f16* Whh16  = (f16*)(ws + 106954752);
    f16* hX     = (f16*)(ws + 113246208);
    unsigned int* flags = (unsigned int*)(ws + 113377280);

    hipLaunchKernelGGL(k_convert, dim3(12288), dim3(256), 0, stream,
                       Wih, Whh, Wih16, Whh16, (u64*)hX, flags);
    hipLaunchKernelGGL(k_pregemm, dim3(24, 128), dim3(256), 0, stream,
                       h_enc, Wih16, bih, GI);
    hipLaunchKernelGGL(k_gru, dim3(NBLK), dim3(256), 0, stream,
                       Whh16, GI, bhh, out, hX, flags);
}

// Round 6
// 1696.424 us; speedup vs baseline: 2.2439x; 1.2705x over previous
//
#include <hip/hip_runtime.h>
#include <math.h>

#define TT 512
#define DD 1024
#define BB 32
#define G3D (3*DD)
#define NBLK 128         // k_gru blocks: 2 batch-groups x 64 col-blocks
#define RG 16            // rows per batch group

typedef _Float16 f16;
typedef _Float16 f16x2 __attribute__((ext_vector_type(2)));
typedef _Float16 f16x4 __attribute__((ext_vector_type(4)));
typedef _Float16 f16x8 __attribute__((ext_vector_type(8)));
typedef float f32x4 __attribute__((ext_vector_type(4)));
typedef unsigned long long u64;

// h exchange: [parity][group][colgroup 0..31][row 0..15][col 0..31] halves.
// Batch rows are INDEPENDENT GRU chains -> broadcast only within a group of
// 16 rows: each block reads 32KB/step instead of 64KB (half the per-CU
// coherent-read volume of the 64-block layout).
// Per-(parity,group) slot = 32*16*32 halves = 32768 B. Total 128 KB.
// Protocol per group (PROVEN r2/r5): publish 4B agent atomics -> vmcnt(0)
// drain -> syncthreads -> per-block epoch flag + 64-way fan-in poll ->
// syncthreads. Tagged/flag-free variants were slower (r3/r4) - do not revisit.
#define HSLOT_BYTES 32768

// ---------------------------------------------------------------- kernel A
__global__ void k_convert(const float* __restrict__ Wih, const float* __restrict__ Whh,
                          f16* __restrict__ Wih16, f16* __restrict__ Whh16,
                          u64* __restrict__ hX, unsigned int* __restrict__ flags) {
    int idx = blockIdx.x * 256 + threadIdx.x;
    int n = G3D * DD;
    if (idx < n) {
        Wih16[idx] = (f16)Wih[idx];
        Whh16[idx] = (f16)Whh[idx];
    }
    if (idx < 16384) hX[idx] = 0ull;          // all 4 slots zero (h0 = 0)
    if (idx < NBLK * 32) flags[idx] = 0u;     // 128 flags, 32-dword spacing
}

// ---------------------------------------------------------------- kernel B
// GI[16384][3072] = h_enc[16384][1024] * Wih^T + b_ih  (fp16 out)
#define BM 128
#define BN 128
#define BK 32
#define LDA 40

__global__ __launch_bounds__(256) void k_pregemm(
    const float* __restrict__ X,
    const f16*   __restrict__ W16,
    const float* __restrict__ bih,
    f16* __restrict__ GI)
{
    __shared__ f16 As[BM * LDA];
    __shared__ f16 Bs[BN * LDA];
    const int tid  = threadIdx.x;
    const int lane = tid & 63;
    const int wave = tid >> 6;
    const int wr = wave >> 1, wc = wave & 1;
    const int m0 = blockIdx.y * BM;
    const int n0 = blockIdx.x * BN;
    const int mfrag = lane & 15;
    const int qfrag = lane >> 4;

    f32x4 acc[4][4] = {};

    for (int kt = 0; kt < DD; kt += BK) {
        __syncthreads();
        {
            int row = tid >> 3;
            int c   = tid & 7;
            #pragma unroll
            for (int p = 0; p < 4; ++p) {
                int r = row + p * 32;
                float4 v = *(const float4*)(X + (size_t)(m0 + r) * DD + kt + c * 4);
                f16x4 hv = { (f16)v.x, (f16)v.y, (f16)v.z, (f16)v.w };
                *(f16x4*)(As + r * LDA + c * 4) = hv;
            }
        }
        {
            int row = tid >> 2;
            int c   = tid & 3;
            #pragma unroll
            for (int p = 0; p < 2; ++p) {
                int r = row + p * 64;
                f16x8 v = *(const f16x8*)(W16 + (size_t)(n0 + r) * DD + kt + c * 8);
                *(f16x8*)(Bs + r * LDA + c * 8) = v;
            }
        }
        __syncthreads();
        f16x8 af[4], bf[4];
        #pragma unroll
        for (int i = 0; i < 4; ++i)
            af[i] = *(const f16x8*)(As + (wr * 64 + i * 16 + mfrag) * LDA + qfrag * 8);
        #pragma unroll
        for (int j = 0; j < 4; ++j)
            bf[j] = *(const f16x8*)(Bs + (wc * 64 + j * 16 + mfrag) * LDA + qfrag * 8);
        #pragma unroll
        for (int i = 0; i < 4; ++i)
            #pragma unroll
            for (int j = 0; j < 4; ++j)
                acc[i][j] = __builtin_amdgcn_mfma_f32_16x16x32_f16(af[i], bf[j], acc[i][j], 0, 0, 0);
    }
    #pragma unroll
    for (int j = 0; j < 4; ++j) {
        int col = n0 + wc * 64 + j * 16 + mfrag;
        float bias = bih[col];
        #pragma unroll
        for (int i = 0; i < 4; ++i) {
            int rowb = m0 + wr * 64 + i * 16 + qfrag * 4;
            #pragma unroll
            for (int r = 0; r < 4; ++r)
                GI[(size_t)(rowb + r) * G3D + col] = (f16)(acc[i][j][r] + bias);
        }
    }
}

// ---------------------------------------------------------------- kernel C
// Persistent recurrent kernel: 128 blocks x 256 threads (4 waves = K-quarters).
// Block bid: group g = bid&1 (batch rows [16g,16g+16)), col-block j = bid>>1
// (h columns [16j,16j+16)). Two groups run independent 64-block barriers.
// W_hh B-fragments in registers (96 VGPR, loop-invariant). gi prefetch sits
// AFTER the af vmcnt(0) so the pre-MFMA wait never includes an HBM gi load.
__global__ __launch_bounds__(256, 1) void k_gru(
    const f16* __restrict__ Whh16,   // [3072][1024]
    const f16* __restrict__ GI,      // [16384][3072]
    const float* __restrict__ bhh,   // [3072]
    float* __restrict__ out,         // [32][512][1024] fp32
    f16* __restrict__ hX,            // [2][2] blocked h slots
    unsigned int* __restrict__ flags)// [128] epoch flags, 32-dword spacing
{
    __shared__ float red[4][3][RG][21];     // 16128 B
    __shared__ float h32[RG][18];
    __shared__ float bh_s[3][16];

    const int tid  = threadIdx.x;
    const int lane = tid & 63;
    const int kq   = tid >> 6;        // wave id = K quarter (256)
    const int bid  = blockIdx.x;
    const int g    = bid & 1;         // batch group
    const int j0   = (bid >> 1) * 16; // owned h columns
    const int row0 = g * RG;          // owned batch rows
    const int mfrag = lane & 15;
    const int qk    = lane >> 4;      // 0..3

    // B-fragments -> registers, once. Lane (mfrag,qk) of wave kq holds
    // W_hh[g'*DD + j0 + mfrag][kq*256 + it*32 + qk*8 ..+8], it=0..7, g'=0..2.
    f16x8 wb[8][3];
    #pragma unroll
    for (int it = 0; it < 8; ++it)
        #pragma unroll
        for (int gt = 0; gt < 3; ++gt)
            wb[it][gt] = *(const f16x8*)(Whh16 + (size_t)(gt * DD + j0 + mfrag) * DD
                                         + kq * 256 + it * 32 + qk * 8);

    for (int i = tid; i < RG * 18; i += 256) ((float*)h32)[i] = 0.f;
    if (tid < 48) bh_s[tid >> 4][tid & 15] = bhh[(tid >> 4) * DD + j0 + (tid & 15)];
    __syncthreads();

    const int bg = (tid >> 3) & 15;   // combine: group-row 0..15 (tid<128 active)
    const int c2 = (tid & 7) * 2;     // combine: col pair 0..14
    const int act = tid < 128;

    // prefetch gi for t=0
    f16x2 giv[3], givn[3];
    if (act)
        #pragma unroll
        for (int gt = 0; gt < 3; ++gt)
            giv[gt] = *(const f16x2*)(GI + (size_t)(row0 + bg) * TT * G3D + gt * DD + j0 + c2);

    for (int t = 0; t < TT; ++t) {
        const int par = t & 1;
        const u64 slotR = (u64)hX + (u64)(par * 2 + g) * HSLOT_BYTES;

        // A-fragments of this group's h rows: 8 coherent dwordx4 per lane;
        // wave covers a dense 1KB region per it -> full 64B lines.
        f16x8 af[8];
        {
            #pragma unroll
            for (int it = 0; it < 8; ++it) {
                u64 addr = slotR + (u64)((((kq * 8 + it) * 16 + mfrag) << 6) + (qk << 4));
                asm volatile("global_load_dwordx4 %0, %1, off sc0 sc1"
                             : "=v"(af[it]) : "v"(addr) : "memory");
            }
        }
        asm volatile("s_waitcnt vmcnt(0)" ::: "memory");
        __builtin_amdgcn_sched_barrier(0);

        // gi prefetch for t+1: issued here so its HBM latency hides under
        // MFMA + reduce + combine, and never sits on the af wait.
        if (act) {
            int tn = (t + 1 < TT) ? t + 1 : t;
            #pragma unroll
            for (int gt = 0; gt < 3; ++gt)
                givn[gt] = *(const f16x2*)(GI + ((size_t)(row0 + bg) * TT + tn) * G3D + gt * DD + j0 + c2);
        }

        // MFMA: B-frags straight from registers; no LDS in this phase.
        f32x4 acc[3] = {};
        #pragma unroll
        for (int it = 0; it < 8; ++it)
            #pragma unroll
            for (int gt = 0; gt < 3; ++gt)
                acc[gt] = __builtin_amdgcn_mfma_f32_16x16x32_f16(
                    af[it], wb[it][gt], acc[gt], 0, 0, 0);

        // dump K-partials. C/D: col=lane&15, row=(lane>>4)*4+reg
        #pragma unroll
        for (int gt = 0; gt < 3; ++gt)
            #pragma unroll
            for (int r = 0; r < 4; ++r)
                red[kq][gt][qk * 4 + r][mfrag] = acc[gt][r];
        __syncthreads();

        // combine: thread (tid<128) -> group-row bg, cols {c2, c2+1}
        if (act) {
            float2 gr = make_float2(0.f, 0.f), gz = gr, gn = gr;
            #pragma unroll
            for (int q = 0; q < 4; ++q) {
                float2 vr = *(const float2*)&red[q][0][bg][c2];
                float2 vz = *(const float2*)&red[q][1][bg][c2];
                float2 vn = *(const float2*)&red[q][2][bg][c2];
                gr.x += vr.x; gr.y += vr.y;
                gz.x += vz.x; gz.y += vz.y;
                gn.x += vn.x; gn.y += vn.y;
            }
            float hnew[2];
            #pragma unroll
            for (int cc = 0; cc < 2; ++cc) {
                float ghr = cc ? gr.y : gr.x;
                float ghz = cc ? gz.y : gz.x;
                float ghn = cc ? gn.y : gn.x;
                float pr = (float)giv[0][cc] + ghr + bh_s[0][c2 + cc];
                float pz = (float)giv[1][cc] + ghz + bh_s[1][c2 + cc];
                float r  = 1.f / (1.f + __expf(-pr));
                float z  = 1.f / (1.f + __expf(-pz));
                float pn = (float)giv[2][cc] + r * (ghn + bh_s[2][c2 + cc]);
                float e  = __expf(-2.f * fabsf(pn));
                float tn = (1.f - e) / (1.f + e);
                tn = pn < 0.f ? -tn : tn;
                float hold = h32[bg][c2 + cc];
                float hn2 = tn + z * (hold - tn);
                h32[bg][c2 + cc] = hn2;
                hnew[cc] = hn2;
            }
            // publish h(t+1): one 4B agent atomic into slot (par^1, g).
            union { unsigned u; f16x2 h; } pk;
            pk.h[0] = (f16)hnew[0]; pk.h[1] = (f16)hnew[1];
            int col = j0 + c2;
            unsigned hidx = ((unsigned)(col >> 5) * 16 + (unsigned)bg) * 16
                          + (unsigned)((col & 31) >> 1);
            unsigned int* hp = (unsigned int*)hX
                             + (size_t)((par ^ 1) * 2 + g) * (HSLOT_BYTES / 4);
            __hip_atomic_store(hp + hidx, pk.u, __ATOMIC_RELAXED, __HIP_MEMORY_SCOPE_AGENT);
            // out store issued NOW so its ack overlaps the h-store ack in the
            // same drain (instead of stalling next step's af vmcnt(0)).
            *(float2*)(out + ((size_t)(row0 + bg) * TT + t) * DD + j0 + c2)
                = make_float2(hnew[0], hnew[1]);
        }

        // release: drain stores, then per-group parallel flag fan-in/out
        __builtin_amdgcn_s_waitcnt(0x0F70);   // vmcnt(0)
        __syncthreads();                      // all waves drained
        if (tid < 64) {
            if (tid == 0)
                __hip_atomic_store(flags + bid * 32, (unsigned)(t + 1),
                                   __ATOMIC_RELAXED, __HIP_MEMORY_SCOPE_AGENT);
            // poll the 64 flags of THIS group: fid = 2*tid + g
            while (__hip_atomic_load(flags + (tid * 2 + g) * 32, __ATOMIC_RELAXED,
                                     __HIP_MEMORY_SCOPE_AGENT) < (unsigned)(t + 1))
                __builtin_amdgcn_s_sleep(1);
        }
        __syncthreads();

        if (act) { giv[0] = givn[0]; giv[1] = givn[1]; giv[2] = givn[2]; }
    }
}

// ---------------------------------------------------------------- launch
extern "C" void kernel_launch(void* const* d_in, const int* in_sizes, int n_in,
                              void* d_out, int out_size, void* d_ws, size_t ws_size,
                              hipStream_t stream) {
    const float* h_enc = (const float*)d_in[0];
    const float* Wih   = (const float*)d_in[1];
    const float* Whh   = (const float*)d_in[2];
    const float* bih   = (const float*)d_in[3];
    const float* bhh   = (const float*)d_in[4];
    float* out = (float*)d_out;

    char* ws = (char*)d_ws;
    // ws layout: GI 100663296 | Wih16 6291456 | Whh16 6291456 | hX 131072 | flags 16384
    f16* GI     = (f16*)(ws);
    f16* Wih16  = (f16*)(ws + 100663296);
    f16* Whh16  = (f16*)(ws + 106954752);
    f16* hX     = (f16*)(ws + 113246208);
    unsigned int* flags = (unsigned int*)(ws + 113377280);

    hipLaunchKernelGGL(k_convert, dim3(12288), dim3(256), 0, stream,
                       Wih, Whh, Wih16, Whh16, (u64*)hX, flags);
    hipLaunchKernelGGL(k_pregemm, dim3(24, 128), dim3(256), 0, stream,
                       h_enc, Wih16, bih, GI);
    hipLaunchKernelGGL(k_gru, dim3(NBLK), dim3(256), 0, stream,
                       Whh16, GI, bhh, out, hX, flags);
}